// Round 2
// baseline (95.926 us; speedup 1.0000x reference)
//
#include <hip/hip_runtime.h>
#include <hip/hip_bf16.h>
#include <stdint.h>

// GraphRec attention aggregator, fused. B=16384, D=50 neighbors, E=64.
// One wave per node b. H1^T = W1^T @ X^T via MFMA (transposed), e_u column
// hoisted to a per-wave c_u (computed once, not per neighbor-tile).
// Aggregation done from the bf16 B-fragments already in registers.

#define BATCH 16384
#define DEG 50

typedef __attribute__((ext_vector_type(8))) short short8;   // 8 bf16 = 4 VGPR
typedef __attribute__((ext_vector_type(4))) float f32x4;

__device__ __forceinline__ short bf(float f) {
    __hip_bfloat16 h = __float2bfloat16(f);       // RNE; compiler pairs into v_cvt_pk_bf16_f32
    return *reinterpret_cast<short*>(&h);
}
__device__ __forceinline__ unsigned pk2(float a, float b) {
    union { unsigned u; unsigned short s[2]; } v;
    v.s[0] = (unsigned short)bf(a);
    v.s[1] = (unsigned short)bf(b);
    return v.u;
}
__device__ __forceinline__ float bf2f(short s) {
    union { float f; unsigned u; } v;
    v.u = (unsigned)(unsigned short)s << 16;
    return v.f;
}
// convert 8 consecutive floats at p -> short8 (frag k-order)
__device__ __forceinline__ short8 cvt_row8(const float* p) {
    f32x4 a = *reinterpret_cast<const f32x4*>(p);
    f32x4 c = *reinterpret_cast<const f32x4*>(p + 4);
    union { short8 s; unsigned u[4]; } v;
    v.u[0] = pk2(a[0], a[1]); v.u[1] = pk2(a[2], a[3]);
    v.u[2] = pk2(c[0], c[1]); v.u[3] = pk2(c[2], c[3]);
    return v.s;
}

// ---- setup: pack W1^T / W2^T MFMA A-fragments (bf16) into d_ws, once ----
// frag f<16: W1, kt=f>>2, t=f&3 ; frag 16+g: W2, kt2=g>>2, t2=g&3.
// A layout (16x16x32): lane l holds A[l&15][8*(l>>4)+j], j=0..7 (row = 16t+r, k = 32kt+8q+j)
__global__ void pack_weights(const float* __restrict__ w1, const float* __restrict__ w2,
                             short8* __restrict__ ws) {
    const int f = blockIdx.x;            // 0..23
    const int lane = threadIdx.x;        // 0..63
    const int q = lane >> 4, r = lane & 15;
    const float* w = (f < 16) ? w1 : w2;
    const int g  = (f < 16) ? f : (f - 16);
    const int kt = g >> 2, t = g & 3;
    short8 s;
    #pragma unroll
    for (int j = 0; j < 8; ++j)
        s[j] = bf(w[(32*kt + 8*q + j)*64 + 16*t + r]);
    ws[f*64 + lane] = s;
}

__global__ __launch_bounds__(256, 4)
void graphrec_fused(const int* __restrict__ nodes, const int* __restrict__ neighbors,
                    const float* __restrict__ u_to_e,
                    const short8* __restrict__ wpk,
                    const float* __restrict__ b1, const float* __restrict__ b2,
                    const float* __restrict__ w3,
                    float* __restrict__ out)
{
    __shared__ short8 lds_a[24][64];                 // [0..15] W1 frags, [16..23] W2 frags
    __shared__ int    lds_nbr[4][64];
    __shared__ unsigned short lds_h1[4][1024];       // per-wave 16x64 bf16, XOR-swizzled

    const int tid  = threadIdx.x;
    const int lane = tid & 63;
    const int wid  = tid >> 6;
    const int q    = lane >> 4;
    const int r    = lane & 15;

    // block-copy pre-packed weight frags (24 KB, coalesced, L2-hot)
    #pragma unroll
    for (int i = 0; i < 6; ++i)
        reinterpret_cast<short8*>(lds_a)[tid + 256*i] = wpk[tid + 256*i];

    const int b    = blockIdx.x * 4 + wid;
    const int node = nodes[b];
    lds_nbr[wid][lane] = (lane < DEG) ? neighbors[b * DEG + lane] : 0;
    __syncthreads();

    // ---- gather neighbor embeddings as B-frags: col m = 16mt+r, k = 32kt+8q+j ----
    short8 xf[4][2];
    #pragma unroll
    for (int mt = 0; mt < 4; ++mt) {
        const int nb = lds_nbr[wid][16*mt + r];
        const float* base = u_to_e + (size_t)nb * 64;
        xf[mt][0] = cvt_row8(base + 8*q);
        xf[mt][1] = cvt_row8(base + 32 + 8*q);
    }

    // ---- c_u[t] = b1 + W1[64:128]^T @ e_u  (once per wave, cols identical) ----
    f32x4 cu[4];
    {
        const float* ub = u_to_e + (size_t)node * 64;
        short8 xu0 = cvt_row8(ub + 8*q);
        short8 xu1 = cvt_row8(ub + 32 + 8*q);
        #pragma unroll
        for (int t = 0; t < 4; ++t) {
            cu[t] = *reinterpret_cast<const f32x4*>(b1 + 16*t + 4*q);
            cu[t] = __builtin_amdgcn_mfma_f32_16x16x32_bf16(lds_a[8  + t][lane], xu0, cu[t], 0, 0, 0);
            cu[t] = __builtin_amdgcn_mfma_f32_16x16x32_bf16(lds_a[12 + t][lane], xu1, cu[t], 0, 0, 0);
        }
    }

    f32x4 b2v[4], w3v[4];
    #pragma unroll
    for (int t = 0; t < 4; ++t) {
        b2v[t] = *reinterpret_cast<const f32x4*>(b2 + 16*t + 4*q);
        w3v[t] = *reinterpret_cast<const f32x4*>(w3 + 16*t + 4*q);
    }

    // ---- per m-tile: layer1 -> relu -> LDS -> layer2 -> score ----
    unsigned short* h1base = lds_h1[wid];
    float sc[4];
    #pragma unroll
    for (int mt = 0; mt < 4; ++mt) {
        f32x4 acc[4] = { cu[0], cu[1], cu[2], cu[3] };
        #pragma unroll
        for (int kt = 0; kt < 2; ++kt)
            #pragma unroll
            for (int t = 0; t < 4; ++t)
                acc[t] = __builtin_amdgcn_mfma_f32_16x16x32_bf16(lds_a[kt*4 + t][lane], xf[mt][kt], acc[t], 0, 0, 0);

        #pragma unroll
        for (int t = 0; t < 4; ++t) {
            unsigned lo = pk2(fmaxf(acc[t][0], 0.f), fmaxf(acc[t][1], 0.f));
            unsigned hi = pk2(fmaxf(acc[t][2], 0.f), fmaxf(acc[t][3], 0.f));
            int off = r * 128 + (((16*t + 4*q) * 2) ^ ((r & 7) << 4));
            *reinterpret_cast<uint2*>((char*)h1base + off) = make_uint2(lo, hi);
        }
        // same-wave LDS RAW (in-order, lgkmcnt-guarded)
        f32x4 acc2[4];
        #pragma unroll
        for (int t2 = 0; t2 < 4; ++t2) acc2[t2] = (f32x4){0.f, 0.f, 0.f, 0.f};
        #pragma unroll
        for (int kt2 = 0; kt2 < 2; ++kt2) {
            int roff = r * 128 + (((32*kt2 + 8*q) * 2) ^ ((r & 7) << 4));
            short8 b2f = *reinterpret_cast<const short8*>((const char*)h1base + roff);
            #pragma unroll
            for (int t2 = 0; t2 < 4; ++t2)
                acc2[t2] = __builtin_amdgcn_mfma_f32_16x16x32_bf16(lds_a[16 + kt2*4 + t2][lane], b2f, acc2[t2], 0, 0, 0);
        }
        float sp = 0.f;
        #pragma unroll
        for (int t2 = 0; t2 < 4; ++t2)
            #pragma unroll
            for (int reg = 0; reg < 4; ++reg)
                sp += fmaxf(acc2[t2][reg] + b2v[t2][reg], 0.f) * w3v[t2][reg];
        sp += __shfl_xor(sp, 16, 64);
        sp += __shfl_xor(sp, 32, 64);
        sc[mt] = sp;                      // score for m = 16*mt + r (replicated over q)
    }

    // ---- softmax over m<50 (cross-lane over r) ----
    float mx = fmaxf(fmaxf(sc[0], sc[1]), sc[2]);
    if (r < 2) mx = fmaxf(mx, sc[3]);
    mx = fmaxf(mx, __shfl_xor(mx, 1, 64));
    mx = fmaxf(mx, __shfl_xor(mx, 2, 64));
    mx = fmaxf(mx, __shfl_xor(mx, 4, 64));
    mx = fmaxf(mx, __shfl_xor(mx, 8, 64));
    float e0 = __expf(sc[0] - mx);
    float e1 = __expf(sc[1] - mx);
    float e2 = __expf(sc[2] - mx);
    float e3 = (r < 2) ? __expf(sc[3] - mx) : 0.f;
    float sum = e0 + e1 + e2 + e3;
    sum += __shfl_xor(sum, 1, 64);
    sum += __shfl_xor(sum, 2, 64);
    sum += __shfl_xor(sum, 4, 64);
    sum += __shfl_xor(sum, 8, 64);
    float inv = 1.f / sum;
    float att[4] = { e0 * inv, e1 * inv, e2 * inv, e3 * inv };

    // ---- aggregation from registers: lane (q,r) holds e_n[16mt+r][32kt+8q+j] ----
    float sagg[16];
    #pragma unroll
    for (int kt = 0; kt < 2; ++kt)
        #pragma unroll
        for (int j = 0; j < 8; ++j) {
            float v = 0.f;
            #pragma unroll
            for (int mt = 0; mt < 4; ++mt)
                v = fmaf(att[mt], bf2f(xf[mt][kt][j]), v);
            sagg[kt*8 + j] = v;
        }
    // reduce over the 16 r-lanes within each q-group
    #pragma unroll
    for (int d = 1; d < 16; d <<= 1)
        #pragma unroll
        for (int i = 0; i < 16; ++i)
            sagg[i] += __shfl_xor(sagg[i], d, 64);

    if (r == 0) {
        float* ob = out + (size_t)b * 64;
        f32x4 o0 = { sagg[0],  sagg[1],  sagg[2],  sagg[3]  };
        f32x4 o1 = { sagg[4],  sagg[5],  sagg[6],  sagg[7]  };
        f32x4 o2 = { sagg[8],  sagg[9],  sagg[10], sagg[11] };
        f32x4 o3 = { sagg[12], sagg[13], sagg[14], sagg[15] };
        *reinterpret_cast<f32x4*>(ob + 8*q)          = o0;
        *reinterpret_cast<f32x4*>(ob + 8*q + 4)      = o1;
        *reinterpret_cast<f32x4*>(ob + 32 + 8*q)     = o2;
        *reinterpret_cast<f32x4*>(ob + 32 + 8*q + 4) = o3;
    }
}

extern "C" void kernel_launch(void* const* d_in, const int* in_sizes, int n_in,
                              void* d_out, int out_size, void* d_ws, size_t ws_size,
                              hipStream_t stream) {
    const int*   nodes     = (const int*)d_in[0];
    const int*   neighbors = (const int*)d_in[1];
    const float* u_to_e    = (const float*)d_in[2];
    const float* w1        = (const float*)d_in[3];
    const float* b1        = (const float*)d_in[4];
    const float* w2        = (const float*)d_in[5];
    const float* b2        = (const float*)d_in[6];
    const float* w3        = (const float*)d_in[7];
    // d_in[8] = b3: constant shift, cancelled exactly by softmax — omitted.

    pack_weights<<<dim3(24), dim3(64), 0, stream>>>(w1, w2, (short8*)d_ws);
    graphrec_fused<<<dim3(BATCH / 4), dim3(256), 0, stream>>>(
        nodes, neighbors, u_to_e, (const short8*)d_ws, b1, b2, w3, (float*)d_out);
}

// Round 3
// 72.308 us; speedup vs baseline: 1.3266x; 1.3266x over previous
//
#include <hip/hip_runtime.h>
#include <hip/hip_bf16.h>
#include <stdint.h>

// GraphRec attention aggregator, fused. B=16384, D=50 neighbors, E=64.
// One wave per node b. H1^T = W1^T @ X^T via MFMA (transposed), e_u column
// hoisted to per-wave c_u. Online-softmax aggregation fused into the m-tile
// loop so xf[mt] dies per-iteration (register pressure: fits 3 waves/SIMD).

#define BATCH 16384
#define DEG 50

typedef __attribute__((ext_vector_type(8))) short short8;   // 8 bf16 = 4 VGPR
typedef __attribute__((ext_vector_type(4))) float f32x4;

__device__ __forceinline__ short bf(float f) {
    __hip_bfloat16 h = __float2bfloat16(f);       // RNE; pairs into v_cvt_pk_bf16_f32
    return *reinterpret_cast<short*>(&h);
}
__device__ __forceinline__ unsigned pk2(float a, float b) {
    union { unsigned u; unsigned short s[2]; } v;
    v.s[0] = (unsigned short)bf(a);
    v.s[1] = (unsigned short)bf(b);
    return v.u;
}
__device__ __forceinline__ float bf2f(short s) {
    union { float f; unsigned u; } v;
    v.u = (unsigned)(unsigned short)s << 16;
    return v.f;
}
__device__ __forceinline__ short8 cvt_row8(const float* p) {
    f32x4 a = *reinterpret_cast<const f32x4*>(p);
    f32x4 c = *reinterpret_cast<const f32x4*>(p + 4);
    union { short8 s; unsigned u[4]; } v;
    v.u[0] = pk2(a[0], a[1]); v.u[1] = pk2(a[2], a[3]);
    v.u[2] = pk2(c[0], c[1]); v.u[3] = pk2(c[2], c[3]);
    return v.s;
}

// ---- setup: pack W1^T / W2^T MFMA A-fragments (bf16) into d_ws, once ----
// frag f<16: W1, kt=f>>2, t=f&3 ; frag 16+g: W2, kt2=g>>2, t2=g&3.
// A layout (16x16x32): lane l holds A[l&15][8*(l>>4)+j], j=0..7
__global__ void pack_weights(const float* __restrict__ w1, const float* __restrict__ w2,
                             short8* __restrict__ ws) {
    const int f = blockIdx.x;            // 0..23
    const int lane = threadIdx.x;        // 0..63
    const int q = lane >> 4, r = lane & 15;
    const float* w = (f < 16) ? w1 : w2;
    const int g  = (f < 16) ? f : (f - 16);
    const int kt = g >> 2, t = g & 3;
    short8 s;
    #pragma unroll
    for (int j = 0; j < 8; ++j)
        s[j] = bf(w[(32*kt + 8*q + j)*64 + 16*t + r]);
    ws[f*64 + lane] = s;
}

__global__ __launch_bounds__(256, 3)
void graphrec_fused(const int* __restrict__ nodes, const int* __restrict__ neighbors,
                    const float* __restrict__ u_to_e,
                    const short8* __restrict__ wpk,
                    const float* __restrict__ b1, const float* __restrict__ b2,
                    const float* __restrict__ w3,
                    float* __restrict__ out)
{
    __shared__ short8 lds_a[24][64];                 // [0..15] W1 frags, [16..23] W2 frags
    __shared__ int    lds_nbr[4][64];
    __shared__ unsigned short lds_h1[4][1024];       // per-wave 16x64 bf16, XOR-swizzled

    const int tid  = threadIdx.x;
    const int lane = tid & 63;
    const int wid  = tid >> 6;
    const int q    = lane >> 4;
    const int r    = lane & 15;

    // block-copy pre-packed weight frags (24 KB, coalesced, L2-hot)
    #pragma unroll
    for (int i = 0; i < 6; ++i)
        reinterpret_cast<short8*>(lds_a)[tid + 256*i] = wpk[tid + 256*i];

    const int b    = blockIdx.x * 4 + wid;
    const int node = nodes[b];
    lds_nbr[wid][lane] = (lane < DEG) ? neighbors[b * DEG + lane] : 0;
    __syncthreads();

    // ---- gather neighbor embeddings as B-frags: col m = 16mt+r, k = 32kt+8q+j ----
    short8 xf[4][2];
    #pragma unroll
    for (int mt = 0; mt < 4; ++mt) {
        const int nb = lds_nbr[wid][16*mt + r];
        const float* base = u_to_e + (size_t)nb * 64;
        xf[mt][0] = cvt_row8(base + 8*q);
        xf[mt][1] = cvt_row8(base + 32 + 8*q);
    }

    // ---- c_u[t] = b1 + W1[64:128]^T @ e_u (once per wave, cols identical) ----
    f32x4 cu[4];
    {
        const float* ub = u_to_e + (size_t)node * 64;
        short8 xu0 = cvt_row8(ub + 8*q);
        short8 xu1 = cvt_row8(ub + 32 + 8*q);
        #pragma unroll
        for (int t = 0; t < 4; ++t) {
            cu[t] = *reinterpret_cast<const f32x4*>(b1 + 16*t + 4*q);
            cu[t] = __builtin_amdgcn_mfma_f32_16x16x32_bf16(lds_a[8  + t][lane], xu0, cu[t], 0, 0, 0);
            cu[t] = __builtin_amdgcn_mfma_f32_16x16x32_bf16(lds_a[12 + t][lane], xu1, cu[t], 0, 0, 0);
        }
    }

    f32x4 b2v[4], w3v[4];
    #pragma unroll
    for (int t = 0; t < 4; ++t) {
        b2v[t] = *reinterpret_cast<const f32x4*>(b2 + 16*t + 4*q);
        w3v[t] = *reinterpret_cast<const f32x4*>(w3 + 16*t + 4*q);
    }

    // ---- m-tile loop: layer1 -> relu -> LDS -> layer2 -> score -> online agg ----
    unsigned short* h1base = lds_h1[wid];
    float agg[16];
    #pragma unroll
    for (int i = 0; i < 16; ++i) agg[i] = 0.f;
    float m_run = -INFINITY, s_run = 0.f;

    #pragma unroll
    for (int mt = 0; mt < 4; ++mt) {
        f32x4 acc[4] = { cu[0], cu[1], cu[2], cu[3] };
        #pragma unroll
        for (int kt = 0; kt < 2; ++kt)
            #pragma unroll
            for (int t = 0; t < 4; ++t)
                acc[t] = __builtin_amdgcn_mfma_f32_16x16x32_bf16(lds_a[kt*4 + t][lane], xf[mt][kt], acc[t], 0, 0, 0);

        #pragma unroll
        for (int t = 0; t < 4; ++t) {
            unsigned lo = pk2(fmaxf(acc[t][0], 0.f), fmaxf(acc[t][1], 0.f));
            unsigned hi = pk2(fmaxf(acc[t][2], 0.f), fmaxf(acc[t][3], 0.f));
            int off = r * 128 + (((16*t + 4*q) * 2) ^ ((r & 7) << 4));
            *reinterpret_cast<uint2*>((char*)h1base + off) = make_uint2(lo, hi);
        }
        // layer 2 (same-wave LDS RAW, lgkmcnt-guarded in-order)
        f32x4 acc2[4];
        #pragma unroll
        for (int t2 = 0; t2 < 4; ++t2) acc2[t2] = (f32x4){0.f, 0.f, 0.f, 0.f};
        #pragma unroll
        for (int kt2 = 0; kt2 < 2; ++kt2) {
            int roff = r * 128 + (((32*kt2 + 8*q) * 2) ^ ((r & 7) << 4));
            short8 b2f = *reinterpret_cast<const short8*>((const char*)h1base + roff);
            #pragma unroll
            for (int t2 = 0; t2 < 4; ++t2)
                acc2[t2] = __builtin_amdgcn_mfma_f32_16x16x32_bf16(lds_a[16 + kt2*4 + t2][lane], b2f, acc2[t2], 0, 0, 0);
        }
        float sp = 0.f;
        #pragma unroll
        for (int t2 = 0; t2 < 4; ++t2)
            #pragma unroll
            for (int reg = 0; reg < 4; ++reg)
                sp += fmaxf(acc2[t2][reg] + b2v[t2][reg], 0.f) * w3v[t2][reg];
        sp += __shfl_xor(sp, 16, 64);
        sp += __shfl_xor(sp, 32, 64);   // score for row m=16mt+r, replicated over q

        // online softmax update
        float v = (mt < 3 || r < 2) ? sp : -INFINITY;
        float tm = v;
        tm = fmaxf(tm, __shfl_xor(tm, 1, 64));
        tm = fmaxf(tm, __shfl_xor(tm, 2, 64));
        tm = fmaxf(tm, __shfl_xor(tm, 4, 64));
        tm = fmaxf(tm, __shfl_xor(tm, 8, 64));
        float m_new = fmaxf(m_run, tm);
        float scale = __expf(m_run - m_new);   // first iter: exp(-inf)=0, agg/s_run are 0
        float w = __expf(v - m_new);           // invalid rows: exp(-inf)=0
        s_run = s_run * scale + w;
        #pragma unroll
        for (int kt = 0; kt < 2; ++kt)
            #pragma unroll
            for (int j = 0; j < 8; ++j)
                agg[kt*8 + j] = fmaf(agg[kt*8 + j], scale, w * bf2f(xf[mt][kt][j]));
        m_run = m_new;
    }

    // ---- normalize + cross-lane reduce over r within each q-group ----
    float sum = s_run;
    sum += __shfl_xor(sum, 1, 64);
    sum += __shfl_xor(sum, 2, 64);
    sum += __shfl_xor(sum, 4, 64);
    sum += __shfl_xor(sum, 8, 64);
    float inv = 1.f / sum;
    #pragma unroll
    for (int i = 0; i < 16; ++i) agg[i] *= inv;
    #pragma unroll
    for (int d = 1; d < 16; d <<= 1)
        #pragma unroll
        for (int i = 0; i < 16; ++i)
            agg[i] += __shfl_xor(agg[i], d, 64);

    if (r == 0) {
        float* ob = out + (size_t)b * 64;
        f32x4 o0 = { agg[0],  agg[1],  agg[2],  agg[3]  };
        f32x4 o1 = { agg[4],  agg[5],  agg[6],  agg[7]  };
        f32x4 o2 = { agg[8],  agg[9],  agg[10], agg[11] };
        f32x4 o3 = { agg[12], agg[13], agg[14], agg[15] };
        *reinterpret_cast<f32x4*>(ob + 8*q)          = o0;
        *reinterpret_cast<f32x4*>(ob + 8*q + 4)      = o1;
        *reinterpret_cast<f32x4*>(ob + 32 + 8*q)     = o2;
        *reinterpret_cast<f32x4*>(ob + 32 + 8*q + 4) = o3;
    }
}

extern "C" void kernel_launch(void* const* d_in, const int* in_sizes, int n_in,
                              void* d_out, int out_size, void* d_ws, size_t ws_size,
                              hipStream_t stream) {
    const int*   nodes     = (const int*)d_in[0];
    const int*   neighbors = (const int*)d_in[1];
    const float* u_to_e    = (const float*)d_in[2];
    const float* w1        = (const float*)d_in[3];
    const float* b1        = (const float*)d_in[4];
    const float* w2        = (const float*)d_in[5];
    const float* b2        = (const float*)d_in[6];
    const float* w3        = (const float*)d_in[7];
    // d_in[8] = b3: constant shift, cancelled exactly by softmax — omitted.

    pack_weights<<<dim3(24), dim3(64), 0, stream>>>(w1, w2, (short8*)d_ws);
    graphrec_fused<<<dim3(BATCH / 4), dim3(256), 0, stream>>>(
        nodes, neighbors, u_to_e, (const short8*)d_ws, b1, b2, w3, (float*)d_out);
}